// Round 11
// baseline (42.442 us; speedup 1.0000x reference)
//
#include <hip/hip_runtime.h>

typedef _Float16 half8 __attribute__((ext_vector_type(8)));
typedef _Float16 half4v __attribute__((ext_vector_type(4)));
typedef float f32x16 __attribute__((ext_vector_type(16)));

#define BOFF 0                    // B slot: 54 frags * 1KB = 55296 B
#define XOFF 55296                // x-tile: 6 rows * 66 cols * 32ch f16 = 25344 B
#define LDS_TOTAL 80640           // 2 blocks/CU

// async global->LDS, 16B/lane; dest is the WAVE-UNIFORM base (HW adds lane*16)
__device__ __forceinline__ void stage16(const void* g, const void* l) {
  __builtin_amdgcn_global_load_lds(
      (const __attribute__((address_space(1))) unsigned int*)(unsigned long long)g,
      (__attribute__((address_space(3))) unsigned int*)(unsigned int)(unsigned long long)l,
      16, 0, 0);
}

// ---------------------------------------------------------------------------
// Pre-pack W [55,64,64] f32 -> f16 MFMA B-fragments, order [nt][ks][cc][l]:
// frag f = ((nt*2+ks)*2 + cc)*54 + l ; elem e = lane*8 + v ;
// value = W[l, (ks*2+cc)*16 + (lane>>5)*8 + v, nt*32 + (lane&31)].
// Bias row (l=54) folded to f32[64] at byte offset 442368.
// ---------------------------------------------------------------------------
__global__ __launch_bounds__(256)
void prepack_kernel(const float* __restrict__ W, _Float16* __restrict__ Bp) {
  const int idx = blockIdx.x * 256 + threadIdx.x;
  if (idx < 221184) {                    // 432 frags * 512 elems
    const int v   = idx & 7;
    const int lam = (idx >> 3) & 63;
    const int f   = idx >> 9;
    const int l   = f % 54;
    const int r   = f / 54;
    const int cc  = r & 1;
    const int ks  = (r >> 1) & 1;
    const int nt  = (r >> 2) & 1;
    const int c   = (ks * 2 + cc) * 16 + (lam >> 5) * 8 + v;
    const int o   = nt * 32 + (lam & 31);
    Bp[idx] = (_Float16)W[(l * 64 + c) * 64 + o];
  } else if (idx < 221184 + 64) {
    const int o = idx - 221184;
    float s = 0.f;
    for (int c = 0; c < 64; ++c) s += W[(54 * 64 + c) * 64 + o];
    ((float*)(Bp + 221184))[o] = s;
  }
}

// ---------------------------------------------------------------------------
// Block = 256 thr = 4 waves = 4 image rows x one nt; wave = 1 row: M=64
// (2 m-tiles of 32), N=32. Grid 512 = 2 blocks/CU (8 waves/CU). K = 4
// temporal rounds (ks x cc, 16 ch). Round 11 delta: accumulators split by
// l-PARITY -> 4 independent MFMA chains per wave (8/SIMD), dependent reuse
// distance 4 MFMAs (~128 cyc) instead of 2. Partial sums added in epilogue.
// ---------------------------------------------------------------------------
__global__ __launch_bounds__(256, 2)
void qconv_kernel(const float* __restrict__ x, const _Float16* __restrict__ Bp,
                  float* __restrict__ out) {
  constexpr int IU[45] = {0,0,0,0,0,0,0,0,0, 1,1,1,1,1,1,1,1, 2,2,2,2,2,2,2,
                          3,3,3,3,3,3, 4,4,4,4,4, 5,5,5,5, 6,6,6, 7,7, 8};
  constexpr int JU[45] = {0,1,2,3,4,5,6,7,8, 1,2,3,4,5,6,7,8, 2,3,4,5,6,7,8,
                          3,4,5,6,7,8, 4,5,6,7,8, 5,6,7,8, 6,7,8, 7,8, 8};

  const int tid  = threadIdx.x;
  const int wave = tid >> 6;               // 0..3 -> image row r0+wave
  const int lane = tid & 63;
  const int colA = lane & 31;
  const int kg   = lane >> 5;

  // XCD-aware bijective remap (512 % 8 == 0)
  const int phys = blockIdx.x;
  const int logical = (phys & 7) * 64 + (phys >> 3);
  const int nt  = logical & 1;
  const int grp = logical >> 1;            // 0..255
  const int b   = grp >> 4;
  const int r0  = (grp & 15) * 4;
  const int r   = r0 + wave;

  __shared__ __align__(16) unsigned char smem[LDS_TOTAL];
  const char* BpB = (const char*)Bp;

  f32x16 acc[2][2] = {};                   // [m-tile][l-parity]: 4 chains
  half8 tap[2][9];                         // 72 VGPRs
  half8 bqE[6], bqO[6];                    // 48 VGPRs, phase ping-pong

#define LOADQ(buf, p)                                                       \
  _Pragma("unroll")                                                         \
  for (int q = 0; q < 6; ++q)                                               \
    buf[q] = *(const half8*)(smem + BOFF + ((p) * 6 + q) * 1024 + lane * 16);

#define MFMA6(buf, l0)                                                      \
  __builtin_amdgcn_s_setprio(1);                                            \
  _Pragma("unroll")                                                         \
  for (int q = 0; q < 6; ++q) {                                             \
    const int l = (l0) + q;                                                 \
    const int pr = l & 1;                 /* compile-time after unroll */   \
    half8 a0, a1;                                                           \
    if (l < 45) { a0 = tap[0][IU[l]] * tap[0][JU[l]];                       \
                  a1 = tap[1][IU[l]] * tap[1][JU[l]]; }                     \
    else        { a0 = tap[0][l - 45]; a1 = tap[1][l - 45]; }               \
    acc[0][pr] = __builtin_amdgcn_mfma_f32_32x32x16_f16(a0, buf[q],         \
                                                        acc[0][pr], 0, 0, 0); \
    acc[1][pr] = __builtin_amdgcn_mfma_f32_32x32x16_f16(a1, buf[q],         \
                                                        acc[1][pr], 0, 0, 0); \
  }                                                                         \
  __builtin_amdgcn_s_setprio(0);

  for (int p = 0; p < 4; ++p) {            // round = (ks, cc) 16-ch chunk
    const int ks = p >> 1;
    const int cc = p & 1;
    __syncthreads();                       // prior round's LDS reads done

    // ---- stage this round's B slot (54 frags) async ---------------------
    const size_t bsrc = (size_t)(((nt * 2 + ks) * 2 + cc) * 54) * 1024;
    for (int f = wave; f < 54; f += 4)
      stage16(BpB + bsrc + (size_t)f * 1024 + lane * 16,
              (char*)smem + BOFF + f * 1024);   // uniform base, HW +lane*16

    // ---- restage x-tile on ks change: 6 rows x 66 cols x 32 ch, f16 -----
    if (cc == 0) {
      for (int idx = tid; idx < 3168; idx += 256) {
        const int row = idx / 528;
        const int rem = idx - row * 528;
        const int col = rem >> 3;
        const int gq  = rem & 7;
        const int hh  = r0 - 1 + row;
        const int ww  = col - 1;
        float4 v = make_float4(0.f, 0.f, 0.f, 0.f);
        if ((unsigned)hh < 64u && (unsigned)ww < 64u)
          v = *(const float4*)(x + ((((size_t)b * 64 + hh) * 64 + ww) * 64
                                    + ks * 32 + gq * 4));
        half4v hv;
        hv[0] = (_Float16)v.x; hv[1] = (_Float16)v.y;
        hv[2] = (_Float16)v.z; hv[3] = (_Float16)v.w;
        const int addr = XOFF + ((row * 4224 + col * 64 + gq * 8)
                                 ^ (((col >> 1) & 3) << 4));
        *(half4v*)(smem + addr) = hv;
      }
    }

    asm volatile("s_waitcnt vmcnt(0)" ::: "memory");   // B landed
    __syncthreads();                                    // x writes visible

    // ---- taps for this 16-ch chunk (8 ch per lane via kg) ---------------
#pragma unroll
    for (int mt = 0; mt < 2; ++mt)
#pragma unroll
      for (int t = 0; t < 9; ++t) {
        const int xrow = wave + t / 3;     // tile rows wave..wave+2
        const int ce   = mt * 32 + colA + (t % 3);
        const int aa = XOFF + ((xrow * 4224 + ce * 64 + cc * 32 + kg * 16)
                               ^ (((ce >> 1) & 3) << 4));
        tap[mt][t] = *(const half8*)(smem + aa);
      }

    // ---- 9 phases x 6 l-steps, ping-pong named buffers ------------------
    LOADQ(bqE, 0);
    LOADQ(bqO, 1);  MFMA6(bqE, 0);
    LOADQ(bqE, 2);  MFMA6(bqO, 6);
    LOADQ(bqO, 3);  MFMA6(bqE, 12);
    LOADQ(bqE, 4);  MFMA6(bqO, 18);
    LOADQ(bqO, 5);  MFMA6(bqE, 24);
    LOADQ(bqE, 6);  MFMA6(bqO, 30);
    LOADQ(bqO, 7);  MFMA6(bqE, 36);
    LOADQ(bqE, 8);  MFMA6(bqO, 42);
                    MFMA6(bqE, 48);
  }

  // ---- epilogue: merge parity chains, bias, coalesced stores -------------
  const float bias = ((const float*)(BpB + 442368))[nt * 32 + colA];
#pragma unroll
  for (int mt = 0; mt < 2; ++mt) {
    float* op = out + (((size_t)b * 64 + r) * 64 + mt * 32) * 64
                    + nt * 32 + colA;
#pragma unroll
    for (int gi = 0; gi < 16; ++gi) {
      const int rowD = (gi & 3) + 8 * (gi >> 2) + 4 * kg;  // pixel within mt
      op[(size_t)rowD * 64] = acc[mt][0][gi] + acc[mt][1][gi] + bias;
    }
  }
}

extern "C" void kernel_launch(void* const* d_in, const int* in_sizes, int n_in,
                              void* d_out, int out_size, void* d_ws, size_t ws_size,
                              hipStream_t stream) {
  const float* x = (const float*)d_in[0];
  const float* W = (const float*)d_in[1];
  float* out     = (float*)d_out;
  _Float16* Bp   = (_Float16*)d_ws;   // 442368 B frags + 256 B bias

  prepack_kernel<<<dim3((221248 + 255) / 256), dim3(256), 0, stream>>>(W, Bp);
  qconv_kernel<<<dim3(512), dim3(256), 0, stream>>>(x, Bp, out);
}

// Round 12
// 42.262 us; speedup vs baseline: 1.0043x; 1.0043x over previous
//
#include <hip/hip_runtime.h>

typedef _Float16 half8 __attribute__((ext_vector_type(8)));
typedef _Float16 half4v __attribute__((ext_vector_type(4)));
typedef float f32x16 __attribute__((ext_vector_type(16)));

#define BOFF 0                    // B slot: 54 frags * 1KB = 55296 B
#define XOFF 55296                // x-tile: 6 rows * 66 cols * 32ch f16 = 25344 B
#define LDS_TOTAL 80640           // 2 blocks/CU

// async global->LDS, 16B/lane; dest is the WAVE-UNIFORM base (HW adds lane*16)
__device__ __forceinline__ void stage16(const void* g, const void* l) {
  __builtin_amdgcn_global_load_lds(
      (const __attribute__((address_space(1))) unsigned int*)(unsigned long long)g,
      (__attribute__((address_space(3))) unsigned int*)(unsigned int)(unsigned long long)l,
      16, 0, 0);
}

// ---------------------------------------------------------------------------
// Pre-pack W [55,64,64] f32 -> f16 MFMA B-fragments, order [nt][ks][cc][l]:
// frag f = ((nt*2+ks)*2 + cc)*54 + l ; elem e = lane*8 + v ;
// value = W[l, (ks*2+cc)*16 + (lane>>5)*8 + v, nt*32 + (lane&31)].
// Bias row (l=54) folded to f32[64] at byte offset 442368.
// ---------------------------------------------------------------------------
__global__ __launch_bounds__(256)
void prepack_kernel(const float* __restrict__ W, _Float16* __restrict__ Bp) {
  const int idx = blockIdx.x * 256 + threadIdx.x;
  if (idx < 221184) {                    // 432 frags * 512 elems
    const int v   = idx & 7;
    const int lam = (idx >> 3) & 63;
    const int f   = idx >> 9;
    const int l   = f % 54;
    const int r   = f / 54;
    const int cc  = r & 1;
    const int ks  = (r >> 1) & 1;
    const int nt  = (r >> 2) & 1;
    const int c   = (ks * 2 + cc) * 16 + (lam >> 5) * 8 + v;
    const int o   = nt * 32 + (lam & 31);
    Bp[idx] = (_Float16)W[(l * 64 + c) * 64 + o];
  } else if (idx < 221184 + 64) {
    const int o = idx - 221184;
    float s = 0.f;
    for (int c = 0; c < 64; ++c) s += W[(54 * 64 + c) * 64 + o];
    ((float*)(Bp + 221184))[o] = s;
  }
}

// ---------------------------------------------------------------------------
// Block = 256 thr = 4 waves = 4 image rows x one nt; wave = 1 row: M=64
// (2 m-tiles of 32), N=32. Grid 512 = 2 blocks/CU (8 waves/CU). K = 4
// temporal rounds (ks x cc, 16 ch). Round-12 delta: the phase schedule is
// PINNED — per phase: issue 6 ds_read_b128 for the next buffer, then
// s_waitcnt lgkmcnt(6) (current buffer landed; DS retires in-order), then
// sched_barrier(0) so hipcc can neither hoist MFMAs above the wait nor sink
// the reads into the cluster, then a pure 12-MFMA cluster under setprio(1).
// ---------------------------------------------------------------------------
__global__ __launch_bounds__(256, 2)
void qconv_kernel(const float* __restrict__ x, const _Float16* __restrict__ Bp,
                  float* __restrict__ out) {
  constexpr int IU[45] = {0,0,0,0,0,0,0,0,0, 1,1,1,1,1,1,1,1, 2,2,2,2,2,2,2,
                          3,3,3,3,3,3, 4,4,4,4,4, 5,5,5,5, 6,6,6, 7,7, 8};
  constexpr int JU[45] = {0,1,2,3,4,5,6,7,8, 1,2,3,4,5,6,7,8, 2,3,4,5,6,7,8,
                          3,4,5,6,7,8, 4,5,6,7,8, 5,6,7,8, 6,7,8, 7,8, 8};

  const int tid  = threadIdx.x;
  const int wave = tid >> 6;               // 0..3 -> image row r0+wave
  const int lane = tid & 63;
  const int colA = lane & 31;
  const int kg   = lane >> 5;

  // XCD-aware bijective remap (512 % 8 == 0)
  const int phys = blockIdx.x;
  const int logical = (phys & 7) * 64 + (phys >> 3);
  const int nt  = logical & 1;
  const int grp = logical >> 1;            // 0..255
  const int b   = grp >> 4;
  const int r0  = (grp & 15) * 4;
  const int r   = r0 + wave;

  __shared__ __align__(16) unsigned char smem[LDS_TOTAL];
  const char* BpB = (const char*)Bp;

  f32x16 acc[2] = {};                      // 2 m-tile chains
  half8 tap[2][9];                         // 72 VGPRs
  half8 bqE[6], bqO[6];                    // 48 VGPRs, phase ping-pong

#define LOADQ(buf, p)                                                       \
  _Pragma("unroll")                                                         \
  for (int q = 0; q < 6; ++q)                                               \
    buf[q] = *(const half8*)(smem + BOFF + ((p) * 6 + q) * 1024 + lane * 16);

#define WAITSB(n)                                                           \
  asm volatile("s_waitcnt lgkmcnt(" #n ")" ::: "memory");                   \
  __builtin_amdgcn_sched_barrier(0);

#define MFMA6(buf, l0)                                                      \
  __builtin_amdgcn_s_setprio(1);                                            \
  _Pragma("unroll")                                                         \
  for (int q = 0; q < 6; ++q) {                                             \
    const int l = (l0) + q;                                                 \
    half8 a0, a1;                                                           \
    if (l < 45) { a0 = tap[0][IU[l]] * tap[0][JU[l]];                       \
                  a1 = tap[1][IU[l]] * tap[1][JU[l]]; }                     \
    else        { a0 = tap[0][l - 45]; a1 = tap[1][l - 45]; }               \
    acc[0] = __builtin_amdgcn_mfma_f32_32x32x16_f16(a0, buf[q], acc[0],     \
                                                    0, 0, 0);               \
    acc[1] = __builtin_amdgcn_mfma_f32_32x32x16_f16(a1, buf[q], acc[1],     \
                                                    0, 0, 0);               \
  }                                                                         \
  __builtin_amdgcn_s_setprio(0);

  for (int p = 0; p < 4; ++p) {            // round = (ks, cc) 16-ch chunk
    const int ks = p >> 1;
    const int cc = p & 1;
    __syncthreads();                       // prior round's LDS reads done

    // ---- stage this round's B slot (54 frags) async ---------------------
    const size_t bsrc = (size_t)(((nt * 2 + ks) * 2 + cc) * 54) * 1024;
    for (int f = wave; f < 54; f += 4)
      stage16(BpB + bsrc + (size_t)f * 1024 + lane * 16,
              (char*)smem + BOFF + f * 1024);   // uniform base, HW +lane*16

    // ---- restage x-tile on ks change: 6 rows x 66 cols x 32 ch, f16 -----
    if (cc == 0) {
      for (int idx = tid; idx < 3168; idx += 256) {
        const int row = idx / 528;
        const int rem = idx - row * 528;
        const int col = rem >> 3;
        const int gq  = rem & 7;
        const int hh  = r0 - 1 + row;
        const int ww  = col - 1;
        float4 v = make_float4(0.f, 0.f, 0.f, 0.f);
        if ((unsigned)hh < 64u && (unsigned)ww < 64u)
          v = *(const float4*)(x + ((((size_t)b * 64 + hh) * 64 + ww) * 64
                                    + ks * 32 + gq * 4));
        half4v hv;
        hv[0] = (_Float16)v.x; hv[1] = (_Float16)v.y;
        hv[2] = (_Float16)v.z; hv[3] = (_Float16)v.w;
        const int addr = XOFF + ((row * 4224 + col * 64 + gq * 8)
                                 ^ (((col >> 1) & 3) << 4));
        *(half4v*)(smem + addr) = hv;
      }
    }

    asm volatile("s_waitcnt vmcnt(0)" ::: "memory");   // B landed
    __syncthreads();                                    // x writes visible

    // ---- taps for this 16-ch chunk (8 ch per lane via kg) ---------------
#pragma unroll
    for (int mt = 0; mt < 2; ++mt)
#pragma unroll
      for (int t = 0; t < 9; ++t) {
        const int xrow = wave + t / 3;     // tile rows wave..wave+2
        const int ce   = mt * 32 + colA + (t % 3);
        const int aa = XOFF + ((xrow * 4224 + ce * 64 + cc * 32 + kg * 16)
                               ^ (((ce >> 1) & 3) << 4));
        tap[mt][t] = *(const half8*)(smem + aa);
      }

    // ---- 9 phases x 6 l-steps, PINNED ping-pong schedule ----------------
    LOADQ(bqE, 0);                         // taps(18) + E(6) outstanding
    LOADQ(bqO, 1);  WAITSB(6);  MFMA6(bqE, 0);    // wait: taps+E landed
    LOADQ(bqE, 2);  WAITSB(6);  MFMA6(bqO, 6);
    LOADQ(bqO, 3);  WAITSB(6);  MFMA6(bqE, 12);
    LOADQ(bqE, 4);  WAITSB(6);  MFMA6(bqO, 18);
    LOADQ(bqO, 5);  WAITSB(6);  MFMA6(bqE, 24);
    LOADQ(bqE, 6);  WAITSB(6);  MFMA6(bqO, 30);
    LOADQ(bqO, 7);  WAITSB(6);  MFMA6(bqE, 36);
    LOADQ(bqE, 8);  WAITSB(6);  MFMA6(bqO, 42);
                    WAITSB(0);  MFMA6(bqE, 48);
  }

  // ---- epilogue: bias + coalesced stores ---------------------------------
  const float bias = ((const float*)(BpB + 442368))[nt * 32 + colA];
#pragma unroll
  for (int mt = 0; mt < 2; ++mt) {
    float* op = out + (((size_t)b * 64 + r) * 64 + mt * 32) * 64
                    + nt * 32 + colA;
#pragma unroll
    for (int gi = 0; gi < 16; ++gi) {
      const int rowD = (gi & 3) + 8 * (gi >> 2) + 4 * kg;  // pixel within mt
      op[(size_t)rowD * 64] = acc[mt][gi] + bias;
    }
  }
}

extern "C" void kernel_launch(void* const* d_in, const int* in_sizes, int n_in,
                              void* d_out, int out_size, void* d_ws, size_t ws_size,
                              hipStream_t stream) {
  const float* x = (const float*)d_in[0];
  const float* W = (const float*)d_in[1];
  float* out     = (float*)d_out;
  _Float16* Bp   = (_Float16*)d_ws;   // 442368 B frags + 256 B bias

  prepack_kernel<<<dim3((221248 + 255) / 256), dim3(256), 0, stream>>>(W, Bp);
  qconv_kernel<<<dim3(512), dim3(256), 0, stream>>>(x, Bp, out);
}